// Round 14
// baseline (267.769 us; speedup 1.0000x reference)
//
#include <hip/hip_runtime.h>

// MonarchLinear — ROUND 14 DIAGNOSTIC (dur inflated ~3x on purpose).
// r13 fused = 91.4us; proven B floor = 46.6; model says A ~5-8us -> ~35us
// UNEXPLAINED. Five theory rounds failed; the kernel has never been profiled
// (91us < 170us harness fills). This round: identical r13 kernel body, rep=3
// (zero-offset trick, d_out written 3x idempotently -> output exact), so the
// fused kernel lands in rocprof top-5 with full counters. Read per-rep:
//   VALUBusy>=60% -> A is VALU-bound | FETCH>>200MB -> R/L over-fetch
//   both low @4.4TB/s -> lockstep phase gap -> half-tile pipeline next
//   LDS conflicts -> t1s pattern | VGPR=128+extra WRITE -> spill.

typedef float f4 __attribute__((ext_vector_type(4)));

namespace {
constexpr int MM    = 68;
constexpr int IN_D  = 256;
constexpr int OUT_D = 4608;
constexpr int TT    = 16;              // tokens per block
constexpr int NTH   = 256;
constexpr int NJ    = 5;
constexpr int XROW  = IN_D + 4;        // 260 floats: x row stride in LDS
constexpr int TPAD  = 4 * MM + 4;      // 276 floats: t1 row stride (16B-aligned)
constexpr int REP   = 3;
}

// phase-A dot worker, two passes over p so only ~9 f4 of x live at once.
template <int P4A, int P4B>
__device__ __forceinline__ void phaseA(const float* __restrict__ xls,
                                       const float* __restrict__ Lrow0,
                                       float* __restrict__ t1w)
{
  {
    f4 xr[P4A];
#pragma unroll
    for (int p4 = 0; p4 < P4A; ++p4) xr[p4] = *(const f4*)(xls + 4 * p4);
#pragma unroll 1
    for (int li = 0; li < 17; ++li) {
      const float* Lp = Lrow0 + (size_t)li * MM;
      f4 s4 = {0.f, 0.f, 0.f, 0.f};
#pragma unroll
      for (int p4 = 0; p4 < P4A; ++p4) {
        f4 Lv = *(const f4*)(Lp + 4 * p4);
        s4.x = fmaf(xr[p4].x, Lv.x, s4.x);
        s4.y = fmaf(xr[p4].y, Lv.y, s4.y);
        s4.z = fmaf(xr[p4].z, Lv.z, s4.z);
        s4.w = fmaf(xr[p4].w, Lv.w, s4.w);
      }
      t1w[li] = (s4.x + s4.y) + (s4.z + s4.w);
    }
  }
  {
    f4 xr[P4B];
#pragma unroll
    for (int p4 = 0; p4 < P4B; ++p4) xr[p4] = *(const f4*)(xls + 4 * (P4A + p4));
#pragma unroll 1
    for (int li = 0; li < 17; ++li) {
      const float* Lp = Lrow0 + (size_t)li * MM + 4 * P4A;
      f4 s4 = {0.f, 0.f, 0.f, 0.f};
#pragma unroll
      for (int p4 = 0; p4 < P4B; ++p4) {
        f4 Lv = *(const f4*)(Lp + 4 * p4);
        s4.x = fmaf(xr[p4].x, Lv.x, s4.x);
        s4.y = fmaf(xr[p4].y, Lv.y, s4.y);
        s4.z = fmaf(xr[p4].z, Lv.z, s4.z);
        s4.w = fmaf(xr[p4].w, Lv.w, s4.w);
      }
      t1w[li] += (s4.x + s4.y) + (s4.z + s4.w);
    }
  }
}

__global__ __launch_bounds__(NTH, 4)
void monarch_fused_rep(const float* __restrict__ x, const float* __restrict__ L,
                       const float* __restrict__ R, const float* __restrict__ bias,
                       float* __restrict__ out, int zero)
{
  __shared__ float xs[TT * XROW];
  __shared__ float t1s[TT * TPAD];
  const int tid = threadIdx.x;
  const long tb = (long)blockIdx.x * TT;

#pragma unroll 1
  for (int rep = 0; rep < REP; ++rep) {
    const float* xb = x   + rep * zero;     // zero==0: defeats hoist/CSE across reps
    float*       ob = out + rep * zero;
    __syncthreads();

    // ---- stage x -> LDS ----
#pragma unroll
    for (int k = 0; k < (TT * IN_D / 4) / NTH; ++k) {
      int i   = k * NTH + tid;
      int tok = i >> 6;
      int pos = i & 63;
      *(f4*)(&xs[tok * XROW + 4 * pos]) = *(const f4*)(xb + (tb + tok) * IN_D + 4 * pos);
    }
    __syncthreads();

    // ---- phase A ----
    {
      const int tok = tid & 15;
      const int seg = tid >> 4;
      const int r   = seg >> 2;
      const int lq  = seg & 3;
      const float* xls   = &xs[tok * XROW + r * MM];
      const float* Lrow0 = L + (size_t)(r * MM + lq * 17) * MM;
      float*       t1w   = &t1s[tok * TPAD + r * MM + lq * 17];
      if (r < 3) phaseA<9, 8>(xls, Lrow0, t1w);
      else       phaseA<9, 4>(xls, Lrow0, t1w);
    }
    __syncthreads();

    // ---- phase B ----
    {
      const int g  = tid / 17;
      const int m  = tid - g * 17;
      const int l4 = 4 * m;

#pragma unroll 1
      for (int j = 0; j < NJ; ++j) {
        const int s = g + 15 * j;
        const bool act = (tid < 255) && (s < MM) && (s < MM - 1 || m < 13);
        const int scol = s * MM + l4;
        f4 R0, R1, R2, R3, bv;
        if (act) {
          R0 = *(const f4*)(R + (size_t)(l4 + 0) * (MM * MM) + (size_t)s * MM);
          R1 = *(const f4*)(R + (size_t)(l4 + 1) * (MM * MM) + (size_t)s * MM);
          R2 = *(const f4*)(R + (size_t)(l4 + 2) * (MM * MM) + (size_t)s * MM);
          R3 = *(const f4*)(R + (size_t)(l4 + 3) * (MM * MM) + (size_t)s * MM);
          bv = *(const f4*)(bias + scol);
        }
#pragma unroll 2
        for (int t = 0; t < TT; ++t) {
          if (act) {
            const float* t1p = t1s + t * TPAD + l4;
            f4 a0 = *(const f4*)(t1p);
            f4 a1 = *(const f4*)(t1p + MM);
            f4 a2 = *(const f4*)(t1p + 2 * MM);
            f4 a3 = *(const f4*)(t1p + 3 * MM);
            f4 o;
            o.x = fmaf(a3.x, R0.w, fmaf(a2.x, R0.z, fmaf(a1.x, R0.y, fmaf(a0.x, R0.x, bv.x))));
            o.y = fmaf(a3.y, R1.w, fmaf(a2.y, R1.z, fmaf(a1.y, R1.y, fmaf(a0.y, R1.x, bv.y))));
            o.z = fmaf(a3.z, R2.w, fmaf(a2.z, R2.z, fmaf(a1.z, R2.y, fmaf(a0.z, R2.x, bv.z))));
            o.w = fmaf(a3.w, R3.w, fmaf(a2.w, R3.z, fmaf(a1.w, R3.y, fmaf(a0.w, R3.x, bv.w))));
            *(f4*)(ob + (tb + t) * OUT_D + scol) = o;
          }
        }
      }
    }
  }
}

extern "C" void kernel_launch(void* const* d_in, const int* in_sizes, int n_in,
                              void* d_out, int out_size, void* d_ws, size_t ws_size,
                              hipStream_t stream) {
  const float* x    = (const float*)d_in[0];
  const float* L    = (const float*)d_in[1];
  const float* R    = (const float*)d_in[2];
  const float* bias = (const float*)d_in[3];
  float* out = (float*)d_out;

  const int ntok = in_sizes[0] / IN_D;     // 16384
  monarch_fused_rep<<<ntok / TT, NTH, 0, stream>>>(x, L, R, bias, out, 0);
}

// Round 15
// 91.343 us; speedup vs baseline: 2.9315x; 2.9315x over previous
//
#include <hip/hip_runtime.h>

// MonarchLinear: x[16384,256] fp32, L[68,68,68], R[68,68,68], bias[4608] -> out[16384,4608] fp32.
//   t1[b,r,l] = sum_p x[b, r*68+p] * L[r,l,p]           (r<4; r==3 only p<52 valid)
//   out[b, s*68+l] = sum_{r<4} t1[b,r,l] * R[l,s,r] + bias[s*68+l]
//
// Round 15. r14 counters: VALUBusy 18%, WRITE ideal (no spill), FETCH 18MB/rep,
// conflicts 7%, HBM 44% -> nothing saturated => phase A is LATENCY-bound: the
// li-rolled two-pass dot = 34 serialized L2-latency stalls/thread at ~2.7
// resident blocks. Fix: p4-OUTER / li-INNER with acc[17]: per p4 iteration all
// 17 Lv loads are independent (one batched latency exposure), 68 FMAs cover the
// next batch. ~100 live regs < 128 cap. Phase B = proven round-7/8 body.

typedef float f4 __attribute__((ext_vector_type(4)));

namespace {
constexpr int MM    = 68;
constexpr int IN_D  = 256;
constexpr int OUT_D = 4608;
constexpr int TT    = 16;              // tokens per block
constexpr int NTH   = 256;
constexpr int NJ    = 5;
constexpr int XROW  = IN_D + 4;        // 260 floats: x row stride in LDS
constexpr int TPAD  = 4 * MM + 4;      // 276 floats: t1 row stride (16B-aligned)
}

// phase-A dot worker: p4 outer, li inner; 17 independent Lv loads per batch.
template <int P4M>
__device__ __forceinline__ void phaseA(const float* __restrict__ xls,
                                       const float* __restrict__ Lrow0,
                                       float* __restrict__ t1w)
{
  float acc[17];
#pragma unroll
  for (int li = 0; li < 17; ++li) acc[li] = 0.f;

#pragma unroll 1
  for (int p4 = 0; p4 < P4M; ++p4) {
    f4 xv = *(const f4*)(xls + 4 * p4);          // LDS
    f4 Lv[17];
#pragma unroll
    for (int li = 0; li < 17; ++li)              // 17 independent global loads
      Lv[li] = *(const f4*)(Lrow0 + (size_t)li * MM + 4 * p4);
#pragma unroll
    for (int li = 0; li < 17; ++li) {            // 68 FMAs cover next batch
      acc[li] = fmaf(xv.x, Lv[li].x, acc[li]);
      acc[li] = fmaf(xv.y, Lv[li].y, acc[li]);
      acc[li] = fmaf(xv.z, Lv[li].z, acc[li]);
      acc[li] = fmaf(xv.w, Lv[li].w, acc[li]);
    }
  }
#pragma unroll
  for (int li = 0; li < 17; ++li) t1w[li] = acc[li];
}

__global__ __launch_bounds__(NTH, 4)     // VGPR cap 128; 4 blocks/CU
void monarch_fused(const float* __restrict__ x, const float* __restrict__ L,
                   const float* __restrict__ R, const float* __restrict__ bias,
                   float* __restrict__ out)
{
  __shared__ float xs[TT * XROW];        // 16,640 B
  __shared__ float t1s[TT * TPAD];       // 17,664 B  (34.3 KB total)
  const int tid = threadIdx.x;
  const long tb = (long)blockIdx.x * TT;

  // ---- stage x -> LDS: 16 rows x 64 f4, 4 full-width coalesced sweeps ----
#pragma unroll
  for (int k = 0; k < (TT * IN_D / 4) / NTH; ++k) {
    int i   = k * NTH + tid;
    int tok = i >> 6;
    int pos = i & 63;
    *(f4*)(&xs[tok * XROW + 4 * pos]) = *(const f4*)(x + (tb + tok) * IN_D + 4 * pos);
  }
  __syncthreads();

  // ---- phase A: t1[tok][r*68 + lq*17 + li] ----
  {
    const int tok = tid & 15;
    const int seg = tid >> 4;            // 0..15; r,lq uniform per 16-lane group
    const int r   = seg >> 2;
    const int lq  = seg & 3;
    const float* xls   = &xs[tok * XROW + r * MM];
    const float* Lrow0 = L + (size_t)(r * MM + lq * 17) * MM;
    float*       t1w   = &t1s[tok * TPAD + r * MM + lq * 17];
    if (r < 3) phaseA<17>(xls, Lrow0, t1w);   // full 68-dot
    else       phaseA<13>(xls, Lrow0, t1w);   // r==3: only p<52 valid
  }
  __syncthreads();

  // ---- phase B: proven round-7/8 stage-2 body (write roofline) ----
  {
    const int g  = tid / 17;
    const int m  = tid - g * 17;
    const int l4 = 4 * m;

#pragma unroll 1                         // j rolled: 20 hoisted regs per iter
    for (int j = 0; j < NJ; ++j) {
      const int s = g + 15 * j;
      // tid==255 (g==15,m==0) duplicates (g=0,j+1); s==67 row has only 52 cols (m<13)
      const bool act = (tid < 255) && (s < MM) && (s < MM - 1 || m < 13);
      const int scol = s * MM + l4;
      f4 R0, R1, R2, R3, bv;
      if (act) {
        R0 = *(const f4*)(R + (size_t)(l4 + 0) * (MM * MM) + (size_t)s * MM);
        R1 = *(const f4*)(R + (size_t)(l4 + 1) * (MM * MM) + (size_t)s * MM);
        R2 = *(const f4*)(R + (size_t)(l4 + 2) * (MM * MM) + (size_t)s * MM);
        R3 = *(const f4*)(R + (size_t)(l4 + 3) * (MM * MM) + (size_t)s * MM);
        bv = *(const f4*)(bias + scol);
      }
#pragma unroll 2
      for (int t = 0; t < TT; ++t) {
        if (act) {
          const float* t1p = t1s + t * TPAD + l4;
          f4 a0 = *(const f4*)(t1p);
          f4 a1 = *(const f4*)(t1p + MM);
          f4 a2 = *(const f4*)(t1p + 2 * MM);
          f4 a3 = *(const f4*)(t1p + 3 * MM);
          f4 o;
          o.x = fmaf(a3.x, R0.w, fmaf(a2.x, R0.z, fmaf(a1.x, R0.y, fmaf(a0.x, R0.x, bv.x))));
          o.y = fmaf(a3.y, R1.w, fmaf(a2.y, R1.z, fmaf(a1.y, R1.y, fmaf(a0.y, R1.x, bv.y))));
          o.z = fmaf(a3.z, R2.w, fmaf(a2.z, R2.z, fmaf(a1.z, R2.y, fmaf(a0.z, R2.x, bv.z))));
          o.w = fmaf(a3.w, R3.w, fmaf(a2.w, R3.z, fmaf(a1.w, R3.y, fmaf(a0.w, R3.x, bv.w))));
          *(f4*)(out + (tb + t) * OUT_D + scol) = o;
        }
      }
    }
  }
}

extern "C" void kernel_launch(void* const* d_in, const int* in_sizes, int n_in,
                              void* d_out, int out_size, void* d_ws, size_t ws_size,
                              hipStream_t stream) {
  const float* x    = (const float*)d_in[0];
  const float* L    = (const float*)d_in[1];
  const float* R    = (const float*)d_in[2];
  const float* bias = (const float*)d_in[3];
  float* out = (float*)d_out;

  const int ntok = in_sizes[0] / IN_D;     // 16384
  monarch_fused<<<ntok / TT, NTH, 0, stream>>>(x, L, R, bias, out);
}